// Round 3
// baseline (268.817 us; speedup 1.0000x reference)
//
#include <hip/hip_runtime.h>

// Problem: B,S,D = 128,256,1024 fp32; BETA = 1.0
constexpr int   Bc   = 128;
constexpr int   Sc   = 256;
constexpr int   Dc   = 1024;
constexpr float BETA = 1.0f;

constexpr int WPW   = 4;                         // s-values per wave
constexpr int SLOTS = (Sc - 2 + WPW - 1) / WPW;  // 64 wave-slots per b
constexpr int WAVES = Bc * SLOTS;                // 8192 waves
constexpr int BLOCK = 256;                       // 4 waves / block
constexpr int GRID  = WAVES / (BLOCK / 64);      // 2048 blocks

__global__ __launch_bounds__(BLOCK, 4) void bridge_loss_kernel(
    const float* __restrict__ bridges,
    const int*   __restrict__ b_inx,
    const int*   __restrict__ neg_i,
    const int*   __restrict__ neg_j,
    float*       __restrict__ out)
{
    const int wid  = (blockIdx.x * BLOCK + threadIdx.x) >> 6;  // global wave id
    const int lane = threadIdx.x & 63;
    const int b    = wid >> 6;              // wid / SLOTS  (SLOTS = 64)
    const int slot = wid & (SLOTS - 1);

    const float th = (float)b_inx[b * Sc];
    const float tt = (float)b_inx[b * Sc + (Sc - 1)];
    const float inv_den = 1.0f / (tt - th);

    const int s0    = 1 + slot * WPW;
    const int rem   = (Sc - 1) - s0;
    const int nIter = (rem < WPW) ? rem : WPW;   // >= 2 for all slots
    const int j0    = s0 - 1;

    // Pre-load all per-s scalars up front (wave-uniform) so the dependent
    // index->gather-address chain is off the per-iteration critical path.
    // Guard tail-slot reads against OOB.
    float tpv[WPW];
    int   nrow[WPW];
#pragma unroll
    for (int i = 0; i < WPW; ++i) {
        const int ii = (i < nIter) ? i : 0;
        tpv[i]  = (float)b_inx[b * Sc + s0 + ii];
        nrow[i] = neg_i[b * (Sc - 2) + j0 + ii] * Sc + neg_j[b * (Sc - 2) + j0 + ii];
    }

    const float4* __restrict__ row4 = (const float4*)bridges;  // row stride Dc/4 = 256

    // head row + (tail-head) delta cached in registers, reused across WPW s-values.
    float4 h[4], dt[4];
    {
        const float4* hp = row4 + (size_t)(b * Sc) * (Dc / 4);
        const float4* tp = row4 + (size_t)(b * Sc + Sc - 1) * (Dc / 4);
#pragma unroll
        for (int k = 0; k < 4; ++k) {
            h[k] = hp[k * 64 + lane];
            float4 t = tp[k * 64 + lane];
            dt[k] = make_float4(t.x - h[k].x, t.y - h[k].y, t.z - h[k].z, t.w - h[k].w);
        }
    }

    float acc = 0.0f;
    float4 pA[4], nA[4], pB[4], nB[4];   // double-buffered row fragments

    auto LOAD = [&](float4 (&P)[4], float4 (&N)[4], int i) {
        const float4* pp = row4 + (size_t)(b * Sc + s0 + i) * (Dc / 4);
        const float4* np = row4 + (size_t)nrow[i] * (Dc / 4);
#pragma unroll
        for (int k = 0; k < 4; ++k) {
            P[k] = pp[k * 64 + lane];
            N[k] = np[k * 64 + lane];
        }
    };

    auto COMPUTE = [&](const float4 (&P)[4], const float4 (&N)[4], int i) {
        const float tp    = tpv[i];
        const float alpha = (tp - th) * inv_den;
        const float sigma = alpha * (tt - tp);
        const float invq  = 1.0f / (2.0f * sigma * sigma);
        float d = 0.0f;   // per-lane (sum xn^2 - sum xp^2)
#pragma unroll
        for (int k = 0; k < 4; ++k) {
            const float m0 = fmaf(alpha, dt[k].x, h[k].x);
            const float m1 = fmaf(alpha, dt[k].y, h[k].y);
            const float m2 = fmaf(alpha, dt[k].z, h[k].z);
            const float m3 = fmaf(alpha, dt[k].w, h[k].w);
            const float xp0 = P[k].x - m0, xp1 = P[k].y - m1,
                        xp2 = P[k].z - m2, xp3 = P[k].w - m3;
            const float xn0 = N[k].x - m0, xn1 = N[k].y - m1,
                        xn2 = N[k].z - m2, xn3 = N[k].w - m3;
            d += xn0 * xn0 - xp0 * xp0;
            d += xn1 * xn1 - xp1 * xp1;
            d += xn2 * xn2 - xp2 * xp2;
            d += xn3 * xn3 - xp3 * xp3;
        }
        // 6-step butterfly on the single difference value
#pragma unroll
        for (int msk = 32; msk >= 1; msk >>= 1) d += __shfl_xor(d, msk);
        const float cur = d * invq + BETA;
        if (cur > 0.0f) acc += cur;
    };

    // Depth-1 software pipeline: prefetch i+1's rows before computing i.
    LOAD(pA, nA, 0);
    if (nIter > 1) LOAD(pB, nB, 1);
    COMPUTE(pA, nA, 0);
    if (nIter > 2) LOAD(pA, nA, 2);
    if (nIter > 1) COMPUTE(pB, nB, 1);
    if (nIter > 3) LOAD(pB, nB, 3);
    if (nIter > 2) COMPUTE(pA, nA, 2);
    if (nIter > 3) COMPUTE(pB, nB, 3);

    if (lane == 0 && acc != 0.0f) {
        atomicAdd(out, acc * (1.0f / (float)Bc));
    }
}

extern "C" void kernel_launch(void* const* d_in, const int* in_sizes, int n_in,
                              void* d_out, int out_size, void* d_ws, size_t ws_size,
                              hipStream_t stream) {
    const float* bridges = (const float*)d_in[0];
    const int*   b_inx   = (const int*)d_in[1];
    const int*   neg_i   = (const int*)d_in[2];
    const int*   neg_j   = (const int*)d_in[3];
    float*       out     = (float*)d_out;

    // d_out is poisoned to 0xAA before every launch — zero it.
    hipMemsetAsync(out, 0, sizeof(float), stream);

    bridge_loss_kernel<<<GRID, BLOCK, 0, stream>>>(bridges, b_inx, neg_i, neg_j, out);
}

// Round 4
// 227.619 us; speedup vs baseline: 1.1810x; 1.1810x over previous
//
#include <hip/hip_runtime.h>

// Problem: B,S,D = 128,256,1024 fp32; BETA = 1.0
constexpr int   Bc   = 128;
constexpr int   Sc   = 256;
constexpr int   Dc   = 1024;
constexpr float BETA = 1.0f;
constexpr int   NP   = Bc * (Sc - 2);   // 32512 pairs (b, j=s-1)
constexpr int   NR   = Bc * Sc;         // 32768 rows

// Workspace layout (bytes), total ~0.87 MB
constexpr size_t OFF_CNT  = 0;        // int[NR]      131072
constexpr size_t OFF_OFFS = 131072;   // int[NR+1]    131076
constexpr size_t OFF_SLOT = 262656;   // int[NP]      130048
constexpr size_t OFF_ROW  = 392704;   // int[NP]      130048
constexpr size_t OFF_LIST = 522752;   // int[NP]      130048
constexpr size_t OFF_POS  = 652800;   // float[NP]    130048
constexpr size_t OFF_NEG  = 782848;   // float[NP]    130048

// ---- A2: count targets per row, record each pair's slot ----
__global__ __launch_bounds__(256) void k_build(
    const int* __restrict__ neg_i, const int* __restrict__ neg_j,
    int* __restrict__ cnt, int* __restrict__ slotv, int* __restrict__ rowid)
{
    int p = blockIdx.x * 256 + threadIdx.x;
    if (p >= NP) return;
    int r = neg_i[p] * Sc + neg_j[p];
    rowid[p] = r;
    slotv[p] = atomicAdd(&cnt[r], 1);
}

// ---- A3: exclusive prefix scan of cnt[NR] -> offs[NR+1] (single block) ----
__global__ __launch_bounds__(1024) void k_scan(
    const int* __restrict__ cnt, int* __restrict__ offs)
{
    __shared__ int part[1024];
    const int t = threadIdx.x;
    const int base = t * 32;          // 1024 * 32 = 32768 = NR
    int s = 0;
#pragma unroll
    for (int i = 0; i < 32; ++i) s += cnt[base + i];
    part[t] = s;
    __syncthreads();
    // Hillis-Steele inclusive scan over 1024 partials
    for (int d = 1; d < 1024; d <<= 1) {
        int v = (t >= d) ? part[t - d] : 0;
        __syncthreads();
        part[t] += v;
        __syncthreads();
    }
    int run = (t == 0) ? 0 : part[t - 1];   // exclusive
#pragma unroll
    for (int i = 0; i < 32; ++i) {
        offs[base + i] = run;
        run += cnt[base + i];
    }
    if (t == 1023) offs[NR] = run;          // = NP
}

// ---- A4: scatter pair ids into per-row lists ----
__global__ __launch_bounds__(256) void k_scatter(
    const int* __restrict__ offs, const int* __restrict__ slotv,
    const int* __restrict__ rowid, int* __restrict__ list)
{
    int p = blockIdx.x * 256 + threadIdx.x;
    if (p >= NP) return;
    int b = p / (Sc - 2);
    int j = p - b * (Sc - 2);
    list[offs[rowid[p]] + slotv[p]] = (b << 8) | j;   // b:7b, j:8b
}

// ---- B: single pass over bridges; one wave per row ----
__global__ __launch_bounds__(256) void k_main(
    const float* __restrict__ bridges, const int* __restrict__ b_inx,
    const int* __restrict__ offs, const int* __restrict__ list,
    float* __restrict__ pos_dis, float* __restrict__ neg_dis)
{
    const int wid  = (blockIdx.x * 256 + threadIdx.x) >> 6;   // row id
    const int lane = threadIdx.x & 63;
    const int r    = wid;                 // 0..NR-1
    const int b    = r >> 8;              // Sc = 256
    const int s    = r & 255;

    const float4* __restrict__ row4 = (const float4*)bridges;  // stride Dc/4=256

    // Load this row once (sequential across waves: 4 x 1KiB wave segments)
    float4 x[4];
    {
        const float4* rp = row4 + (size_t)r * (Dc / 4);
#pragma unroll
        for (int k = 0; k < 4; ++k) x[k] = rp[k * 64 + lane];
    }

    const int beg = offs[r], end = offs[r + 1];

    // POS role: this row is the pos sample of pair (b, s-1)
    if (s >= 1 && s <= Sc - 2) {
        const float th = (float)b_inx[b * Sc];
        const float tt = (float)b_inx[b * Sc + (Sc - 1)];
        const float tp = (float)b_inx[b * Sc + s];
        const float alpha = (tp - th) / (tt - th);
        const float sigma = alpha * (tt - tp);
        const float inv   = 1.0f / (2.0f * sigma * sigma);
        const float4* hp = row4 + (size_t)(b * Sc) * (Dc / 4);
        const float4* tq = row4 + (size_t)(b * Sc + Sc - 1) * (Dc / 4);
        float d = 0.0f;
#pragma unroll
        for (int k = 0; k < 4; ++k) {
            const float4 h = hp[k * 64 + lane];
            const float4 t = tq[k * 64 + lane];
            const float m0 = fmaf(alpha, t.x - h.x, h.x);
            const float m1 = fmaf(alpha, t.y - h.y, h.y);
            const float m2 = fmaf(alpha, t.z - h.z, h.z);
            const float m3 = fmaf(alpha, t.w - h.w, h.w);
            const float e0 = x[k].x - m0, e1 = x[k].y - m1;
            const float e2 = x[k].z - m2, e3 = x[k].w - m3;
            d += e0 * e0 + e1 * e1 + e2 * e2 + e3 * e3;
        }
#pragma unroll
        for (int m = 32; m >= 1; m >>= 1) d += __shfl_xor(d, m);
        if (lane == 0) pos_dis[b * (Sc - 2) + (s - 1)] = -d * inv;
    }

    // NEG roles: every pair whose gathered neg sample is this row
    for (int q = beg; q < end; ++q) {
        const int e  = list[q];
        const int bb = e >> 8;
        const int jj = e & 255;
        const int ss = jj + 1;
        const float th = (float)b_inx[bb * Sc];
        const float tt = (float)b_inx[bb * Sc + (Sc - 1)];
        const float tp = (float)b_inx[bb * Sc + ss];
        const float alpha = (tp - th) / (tt - th);
        const float sigma = alpha * (tt - tp);
        const float inv   = 1.0f / (2.0f * sigma * sigma);
        const float4* hp = row4 + (size_t)(bb * Sc) * (Dc / 4);
        const float4* tq = row4 + (size_t)(bb * Sc + Sc - 1) * (Dc / 4);
        float d = 0.0f;
#pragma unroll
        for (int k = 0; k < 4; ++k) {
            const float4 h = hp[k * 64 + lane];
            const float4 t = tq[k * 64 + lane];
            const float m0 = fmaf(alpha, t.x - h.x, h.x);
            const float m1 = fmaf(alpha, t.y - h.y, h.y);
            const float m2 = fmaf(alpha, t.z - h.z, h.z);
            const float m3 = fmaf(alpha, t.w - h.w, h.w);
            const float e0 = x[k].x - m0, e1 = x[k].y - m1;
            const float e2 = x[k].z - m2, e3 = x[k].w - m3;
            d += e0 * e0 + e1 * e1 + e2 * e2 + e3 * e3;
        }
#pragma unroll
        for (int m = 32; m >= 1; m >>= 1) d += __shfl_xor(d, m);
        if (lane == 0) neg_dis[bb * (Sc - 2) + jj] = -d * inv;
    }
}

// ---- C: final hinge-sum (deterministic, single block) ----
__global__ __launch_bounds__(1024) void k_reduce(
    const float* __restrict__ pos_dis, const float* __restrict__ neg_dis,
    float* __restrict__ out)
{
    __shared__ float red[1024];
    const int t = threadIdx.x;
    float a = 0.0f;
    for (int p = t; p < NP; p += 1024) {
        const float cur = pos_dis[p] - neg_dis[p] + BETA;
        if (cur > 0.0f) a += cur;
    }
    red[t] = a;
    __syncthreads();
    for (int d = 512; d > 0; d >>= 1) {
        if (t < d) red[t] += red[t + d];
        __syncthreads();
    }
    if (t == 0) out[0] = red[0] * (1.0f / (float)Bc);
}

extern "C" void kernel_launch(void* const* d_in, const int* in_sizes, int n_in,
                              void* d_out, int out_size, void* d_ws, size_t ws_size,
                              hipStream_t stream) {
    const float* bridges = (const float*)d_in[0];
    const int*   b_inx   = (const int*)d_in[1];
    const int*   neg_i   = (const int*)d_in[2];
    const int*   neg_j   = (const int*)d_in[3];
    float*       out     = (float*)d_out;

    char* ws = (char*)d_ws;
    int*   cnt     = (int*)(ws + OFF_CNT);
    int*   offs    = (int*)(ws + OFF_OFFS);
    int*   slotv   = (int*)(ws + OFF_SLOT);
    int*   rowid   = (int*)(ws + OFF_ROW);
    int*   list    = (int*)(ws + OFF_LIST);
    float* pos_dis = (float*)(ws + OFF_POS);
    float* neg_dis = (float*)(ws + OFF_NEG);

    hipMemsetAsync(cnt, 0, NR * sizeof(int), stream);
    k_build  <<<(NP + 255) / 256, 256, 0, stream>>>(neg_i, neg_j, cnt, slotv, rowid);
    k_scan   <<<1, 1024, 0, stream>>>(cnt, offs);
    k_scatter<<<(NP + 255) / 256, 256, 0, stream>>>(offs, slotv, rowid, list);
    k_main   <<<NR / 4, 256, 0, stream>>>(bridges, b_inx, offs, list, pos_dis, neg_dis);
    k_reduce <<<1, 1024, 0, stream>>>(pos_dis, neg_dis, out);
}

// Round 5
// 217.908 us; speedup vs baseline: 1.2336x; 1.0446x over previous
//
#include <hip/hip_runtime.h>

// Problem: B,S,D = 128,256,1024 fp32; BETA = 1.0
constexpr int   Bc   = 128;
constexpr int   Sc   = 256;
constexpr int   Dc   = 1024;
constexpr float BETA = 1.0f;
constexpr int   NP   = Bc * (Sc - 2);   // 32512 pairs (b, j=s-1)
constexpr int   NR   = Bc * Sc;         // 32768 rows
constexpr int   CAP  = 32;              // bucket capacity per row (Poisson(1) -> never hit)

// Workspace layout (bytes); ws is ~512 MB, we use ~4.6 MB
constexpr size_t OFF_CNT  = 0;                        // int[NR]        131072
constexpr size_t OFF_OVFC = 131072;                   // int[1]
constexpr size_t OFF_LIST = 131200;                   // int[NR*CAP]    4 MiB
constexpr size_t OFF_OVFL = OFF_LIST + (size_t)NR * CAP * 4;   // int[NP]
constexpr size_t OFF_POS  = OFF_OVFL + (size_t)NP * 4;         // float[NP]
constexpr size_t OFF_NEG  = OFF_POS  + (size_t)NP * 4;         // float[NP]

// ---- A: bucket pairs by their neg target row (no scan, no scatter) ----
__global__ __launch_bounds__(256) void k_build(
    const int* __restrict__ neg_i, const int* __restrict__ neg_j,
    int* __restrict__ cnt, int* __restrict__ list,
    int* __restrict__ ovf_cnt, int* __restrict__ ovf_list)
{
    const int p = blockIdx.x * 256 + threadIdx.x;   // grid sized exactly NP/256
    const int b = p / (Sc - 2);
    const int j = p - b * (Sc - 2);
    const int r = neg_i[p] * Sc + neg_j[p];
    const int slot = atomicAdd(&cnt[r], 1);
    if (slot < CAP) {
        list[r * CAP + slot] = (b << 8) | j;
    } else {
        ovf_list[atomicAdd(ovf_cnt, 1)] = p;   // store pair id for direct gather
    }
}

// ---- B: single pass over bridges; one wave per row ----
__global__ __launch_bounds__(256) void k_main(
    const float* __restrict__ bridges, const int* __restrict__ b_inx,
    const int* __restrict__ cnt, const int* __restrict__ list,
    float* __restrict__ pos_dis, float* __restrict__ neg_dis)
{
    const int r    = (blockIdx.x * 256 + threadIdx.x) >> 6;   // row id
    const int lane = threadIdx.x & 63;
    const int b    = r >> 8;              // Sc = 256
    const int s    = r & 255;

    const float4* __restrict__ row4 = (const float4*)bridges;  // stride Dc/4=256

    // Load this row once (sequential across waves: 4 x 1KiB wave segments)
    float4 x[4];
    {
        const float4* rp = row4 + (size_t)r * (Dc / 4);
#pragma unroll
        for (int k = 0; k < 4; ++k) x[k] = rp[k * 64 + lane];
    }

    const int nneg = min(cnt[r], CAP);

    // POS role: this row is the pos sample of pair (b, s-1)
    if (s >= 1 && s <= Sc - 2) {
        const float th = (float)b_inx[b * Sc];
        const float tt = (float)b_inx[b * Sc + (Sc - 1)];
        const float tp = (float)b_inx[b * Sc + s];
        const float alpha = (tp - th) / (tt - th);
        const float sigma = alpha * (tt - tp);
        const float inv   = 1.0f / (2.0f * sigma * sigma);
        const float4* hp = row4 + (size_t)(b * Sc) * (Dc / 4);
        const float4* tq = row4 + (size_t)(b * Sc + Sc - 1) * (Dc / 4);
        float d = 0.0f;
#pragma unroll
        for (int k = 0; k < 4; ++k) {
            const float4 h = hp[k * 64 + lane];
            const float4 t = tq[k * 64 + lane];
            const float m0 = fmaf(alpha, t.x - h.x, h.x);
            const float m1 = fmaf(alpha, t.y - h.y, h.y);
            const float m2 = fmaf(alpha, t.z - h.z, h.z);
            const float m3 = fmaf(alpha, t.w - h.w, h.w);
            const float e0 = x[k].x - m0, e1 = x[k].y - m1;
            const float e2 = x[k].z - m2, e3 = x[k].w - m3;
            d += e0 * e0 + e1 * e1 + e2 * e2 + e3 * e3;
        }
#pragma unroll
        for (int m = 32; m >= 1; m >>= 1) d += __shfl_xor(d, m);
        if (lane == 0) pos_dis[b * (Sc - 2) + (s - 1)] = -d * inv;
    }

    // NEG roles: every pair whose gathered neg sample is this row
    for (int q = 0; q < nneg; ++q) {
        const int e  = list[r * CAP + q];
        const int bb = e >> 8;
        const int jj = e & 255;
        const int ss = jj + 1;
        const float th = (float)b_inx[bb * Sc];
        const float tt = (float)b_inx[bb * Sc + (Sc - 1)];
        const float tp = (float)b_inx[bb * Sc + ss];
        const float alpha = (tp - th) / (tt - th);
        const float sigma = alpha * (tt - tp);
        const float inv   = 1.0f / (2.0f * sigma * sigma);
        const float4* hp = row4 + (size_t)(bb * Sc) * (Dc / 4);
        const float4* tq = row4 + (size_t)(bb * Sc + Sc - 1) * (Dc / 4);
        float d = 0.0f;
#pragma unroll
        for (int k = 0; k < 4; ++k) {
            const float4 h = hp[k * 64 + lane];
            const float4 t = tq[k * 64 + lane];
            const float m0 = fmaf(alpha, t.x - h.x, h.x);
            const float m1 = fmaf(alpha, t.y - h.y, h.y);
            const float m2 = fmaf(alpha, t.z - h.z, h.z);
            const float m3 = fmaf(alpha, t.w - h.w, h.w);
            const float e0 = x[k].x - m0, e1 = x[k].y - m1;
            const float e2 = x[k].z - m2, e3 = x[k].w - m3;
            d += e0 * e0 + e1 * e1 + e2 * e2 + e3 * e3;
        }
#pragma unroll
        for (int m = 32; m >= 1; m >>= 1) d += __shfl_xor(d, m);
        if (lane == 0) neg_dis[bb * (Sc - 2) + jj] = -d * inv;
    }
}

// ---- C: overflow cleanup (expected empty) + final hinge-sum, one block ----
__global__ __launch_bounds__(1024) void k_reduce(
    const float* __restrict__ bridges, const int* __restrict__ b_inx,
    const int* __restrict__ neg_i, const int* __restrict__ neg_j,
    const int* __restrict__ ovf_cnt, const int* __restrict__ ovf_list,
    const float* __restrict__ pos_dis, float* __restrict__ neg_dis,
    float* __restrict__ out)
{
    const int t    = threadIdx.x;
    const int wave = t >> 6;
    const int lane = t & 63;
    const float4* __restrict__ row4 = (const float4*)bridges;

    // Phase A: pairs whose bucket overflowed (expected 0) — direct gather
    const int novf = *ovf_cnt;
    for (int e = wave; e < novf; e += 16) {
        const int p  = ovf_list[e];
        const int bb = p / (Sc - 2);
        const int jj = p - bb * (Sc - 2);
        const int ss = jj + 1;
        const int r  = neg_i[p] * Sc + neg_j[p];
        const float th = (float)b_inx[bb * Sc];
        const float tt = (float)b_inx[bb * Sc + (Sc - 1)];
        const float tp = (float)b_inx[bb * Sc + ss];
        const float alpha = (tp - th) / (tt - th);
        const float sigma = alpha * (tt - tp);
        const float inv   = 1.0f / (2.0f * sigma * sigma);
        const float4* xp = row4 + (size_t)r * (Dc / 4);
        const float4* hp = row4 + (size_t)(bb * Sc) * (Dc / 4);
        const float4* tq = row4 + (size_t)(bb * Sc + Sc - 1) * (Dc / 4);
        float d = 0.0f;
#pragma unroll
        for (int k = 0; k < 4; ++k) {
            const float4 x = xp[k * 64 + lane];
            const float4 h = hp[k * 64 + lane];
            const float4 tv = tq[k * 64 + lane];
            const float m0 = fmaf(alpha, tv.x - h.x, h.x);
            const float m1 = fmaf(alpha, tv.y - h.y, h.y);
            const float m2 = fmaf(alpha, tv.z - h.z, h.z);
            const float m3 = fmaf(alpha, tv.w - h.w, h.w);
            const float e0 = x.x - m0, e1 = x.y - m1;
            const float e2 = x.z - m2, e3 = x.w - m3;
            d += e0 * e0 + e1 * e1 + e2 * e2 + e3 * e3;
        }
#pragma unroll
        for (int m = 32; m >= 1; m >>= 1) d += __shfl_xor(d, m);
        if (lane == 0) neg_dis[bb * (Sc - 2) + jj] = -d * inv;
    }
    __syncthreads();

    // Phase B: hinge sum
    __shared__ float red[1024];
    float a = 0.0f;
    for (int p = t; p < NP; p += 1024) {
        const float cur = pos_dis[p] - neg_dis[p] + BETA;
        if (cur > 0.0f) a += cur;
    }
    red[t] = a;
    __syncthreads();
    for (int d = 512; d > 0; d >>= 1) {
        if (t < d) red[t] += red[t + d];
        __syncthreads();
    }
    if (t == 0) out[0] = red[0] * (1.0f / (float)Bc);
}

extern "C" void kernel_launch(void* const* d_in, const int* in_sizes, int n_in,
                              void* d_out, int out_size, void* d_ws, size_t ws_size,
                              hipStream_t stream) {
    const float* bridges = (const float*)d_in[0];
    const int*   b_inx   = (const int*)d_in[1];
    const int*   neg_i   = (const int*)d_in[2];
    const int*   neg_j   = (const int*)d_in[3];
    float*       out     = (float*)d_out;

    char* ws = (char*)d_ws;
    int*   cnt      = (int*)(ws + OFF_CNT);
    int*   ovf_cnt  = (int*)(ws + OFF_OVFC);
    int*   list     = (int*)(ws + OFF_LIST);
    int*   ovf_list = (int*)(ws + OFF_OVFL);
    float* pos_dis  = (float*)(ws + OFF_POS);
    float* neg_dis  = (float*)(ws + OFF_NEG);

    // zero cnt[NR] and ovf_cnt (contiguous)
    hipMemsetAsync(ws, 0, OFF_OVFC + 4, stream);
    k_build <<<NP / 256, 256, 0, stream>>>(neg_i, neg_j, cnt, list, ovf_cnt, ovf_list);
    k_main  <<<NR / 4, 256, 0, stream>>>(bridges, b_inx, cnt, list, pos_dis, neg_dis);
    k_reduce<<<1, 1024, 0, stream>>>(bridges, b_inx, neg_i, neg_j,
                                     ovf_cnt, ovf_list, pos_dis, neg_dis, out);
}

// Round 6
// 208.046 us; speedup vs baseline: 1.2921x; 1.0474x over previous
//
#include <hip/hip_runtime.h>
#include <math.h>

// Problem: B,S,D = 128,256,1024 fp32; BETA = 1.0
constexpr int   Bc   = 128;
constexpr int   Sc   = 256;
constexpr int   Dc   = 1024;
constexpr float BETA = 1.0f;
constexpr int   SP   = Sc - 2;          // 254 pairs per batch
constexpr int   NP   = Bc * SP;         // 32512 pairs
constexpr int   NR   = Bc * Sc;         // 32768 rows
constexpr int   CAP  = 8;               // bucket capacity (Poisson(~1); overflow -> exact fallback)

// Workspace layout (bytes); ws is 512 MiB, we use ~4.8 MiB
constexpr size_t OFF_CNT  = 0;                                  // int[NR]
constexpr size_t OFF_REC  = 131072;                             // float4[NR*CAP] 4 MiB
constexpr size_t OFF_PPAR = OFF_REC + (size_t)NR * CAP * 16;    // float2[NP]
constexpr size_t OFF_PD   = OFF_PPAR + (size_t)NP * 8;          // float[NP]
constexpr size_t OFF_ND   = OFF_PD + (size_t)NP * 4;            // float[NP]

// ---- A: per-pair params + bucket by neg target row ----
__global__ __launch_bounds__(256) void k_build(
    const int* __restrict__ b_inx, const int* __restrict__ neg_i,
    const int* __restrict__ neg_j, int* __restrict__ cnt,
    float4* __restrict__ rec, float2* __restrict__ ppar,
    float* __restrict__ neg_dis, float* __restrict__ out)
{
    const int p = blockIdx.x * 256 + threadIdx.x;   // grid = NP/256 exactly
    if (p == 0) out[0] = 0.0f;                      // stream-ordered before k_hinge
    const int b = p / SP;
    const int j = p - b * SP;
    const int s = j + 1;
    const float th = (float)b_inx[b * Sc];
    const float tt = (float)b_inx[b * Sc + (Sc - 1)];
    const float tp = (float)b_inx[b * Sc + s];
    const float alpha = (tp - th) / (tt - th);
    const float sigma = alpha * (tt - tp);
    const float inv   = 1.0f / (2.0f * sigma * sigma);
    ppar[p] = make_float2(alpha, inv);
    const int r = neg_i[p] * Sc + neg_j[p];
    const int slot = atomicAdd(&cnt[r], 1);
    if (slot < CAP) {
        rec[r * CAP + slot] = make_float4(__int_as_float((b << 8) | j), alpha, inv, 0.0f);
    } else {
        neg_dis[p] = INFINITY;   // sentinel: k_hinge recomputes exactly
    }
}

// ---- B: single pass over bridges; one wave per row ----
__global__ __launch_bounds__(256) void k_main(
    const float* __restrict__ bridges,
    const int* __restrict__ cnt, const float4* __restrict__ rec,
    const float2* __restrict__ ppar,
    float* __restrict__ pos_dis, float* __restrict__ neg_dis)
{
    const int r    = (blockIdx.x * 256 + threadIdx.x) >> 6;  // row id
    const int lane = threadIdx.x & 63;
    const int b    = r >> 8;               // Sc = 256
    const int s    = r & 255;

    const float4* __restrict__ row4 = (const float4*)bridges;  // stride Dc/4 = 256

    // This row: 4 x 1 KiB contiguous wave segments
    float4 x[4];
    {
        const float4* rp = row4 + (size_t)r * (Dc / 4);
#pragma unroll
        for (int k = 0; k < 4; ++k) x[k] = rp[k * 64 + lane];
    }

    const int nneg = min(cnt[r], CAP);
    // Issue first neg record load early (safe even if nneg==0; not deref'd then)
    float4 rc = rec[r * CAP];

    // own-batch head/tail base pointers (L1-resident across the block's 4 waves)
    const float4* hp = row4 + (size_t)(b * Sc) * (Dc / 4);
    const float4* tq = row4 + (size_t)(b * Sc + Sc - 1) * (Dc / 4);

    // POS role
    if (s >= 1 && s <= Sc - 2) {
        const float2 pp    = ppar[b * SP + (s - 1)];
        const float  alpha = pp.x, inv = pp.y;
        float d = 0.0f;
#pragma unroll
        for (int k = 0; k < 4; ++k) {
            const float4 h = hp[k * 64 + lane];
            const float4 t = tq[k * 64 + lane];
            const float m0 = fmaf(alpha, t.x - h.x, h.x);
            const float m1 = fmaf(alpha, t.y - h.y, h.y);
            const float m2 = fmaf(alpha, t.z - h.z, h.z);
            const float m3 = fmaf(alpha, t.w - h.w, h.w);
            const float e0 = x[k].x - m0, e1 = x[k].y - m1;
            const float e2 = x[k].z - m2, e3 = x[k].w - m3;
            d += e0 * e0 + e1 * e1 + e2 * e2 + e3 * e3;
        }
#pragma unroll
        for (int m = 32; m >= 1; m >>= 1) d += __shfl_xor(d, m);
        if (lane == 0) pos_dis[b * SP + (s - 1)] = -d * inv;
    }

    // NEG roles: pairs whose gathered neg sample is this row
    for (int q = 0; q < nneg; ++q) {
        const int   e     = __float_as_int(rc.x);
        const float alpha = rc.y, inv = rc.z;
        const int   bb = e >> 8;
        const int   jj = e & 255;
        const float4* hb = row4 + (size_t)(bb * Sc) * (Dc / 4);
        const float4* tb = row4 + (size_t)(bb * Sc + Sc - 1) * (Dc / 4);
        if (q + 1 < nneg) rc = rec[r * CAP + q + 1];   // prefetch next record
        float d = 0.0f;
#pragma unroll
        for (int k = 0; k < 4; ++k) {
            const float4 h = hb[k * 64 + lane];
            const float4 t = tb[k * 64 + lane];
            const float m0 = fmaf(alpha, t.x - h.x, h.x);
            const float m1 = fmaf(alpha, t.y - h.y, h.y);
            const float m2 = fmaf(alpha, t.z - h.z, h.z);
            const float m3 = fmaf(alpha, t.w - h.w, h.w);
            const float e0 = x[k].x - m0, e1 = x[k].y - m1;
            const float e2 = x[k].z - m2, e3 = x[k].w - m3;
            d += e0 * e0 + e1 * e1 + e2 * e2 + e3 * e3;
        }
#pragma unroll
        for (int m = 32; m >= 1; m >>= 1) d += __shfl_xor(d, m);
        if (lane == 0) neg_dis[bb * SP + jj] = -d * inv;
    }
}

// ---- C: hinge sum, 128 blocks, one atomicAdd per block ----
__global__ __launch_bounds__(256) void k_hinge(
    const float* __restrict__ bridges, const int* __restrict__ b_inx,
    const int* __restrict__ neg_i, const int* __restrict__ neg_j,
    const float* __restrict__ pos_dis, const float* __restrict__ neg_dis,
    float* __restrict__ out)
{
    float a = 0.0f;
    for (int p = blockIdx.x * 256 + threadIdx.x; p < NP; p += gridDim.x * 256) {
        float nd = neg_dis[p];
        if (__builtin_isinf(nd)) {
            // exact fallback for bucket overflow (expected count: 0)
            const int bb = p / SP, jj = p - bb * SP, ss = jj + 1;
            const int r  = neg_i[p] * Sc + neg_j[p];
            const float th = (float)b_inx[bb * Sc];
            const float tt = (float)b_inx[bb * Sc + (Sc - 1)];
            const float tp = (float)b_inx[bb * Sc + ss];
            const float alpha = (tp - th) / (tt - th);
            const float sigma = alpha * (tt - tp);
            const float inv   = 1.0f / (2.0f * sigma * sigma);
            const float* xr = bridges + (size_t)r * Dc;
            const float* hr = bridges + (size_t)(bb * Sc) * Dc;
            const float* tr = bridges + (size_t)(bb * Sc + Sc - 1) * Dc;
            float d = 0.0f;
            for (int k = 0; k < Dc; ++k) {
                const float h = hr[k];
                const float m = fmaf(alpha, tr[k] - h, h);
                const float e = xr[k] - m;
                d += e * e;
            }
            nd = -d * inv;
        }
        const float cur = pos_dis[p] - nd + BETA;
        if (cur > 0.0f) a += cur;
    }
    __shared__ float red[4];
#pragma unroll
    for (int m = 32; m >= 1; m >>= 1) a += __shfl_xor(a, m);
    if ((threadIdx.x & 63) == 0) red[threadIdx.x >> 6] = a;
    __syncthreads();
    if (threadIdx.x == 0) {
        const float ssum = red[0] + red[1] + red[2] + red[3];
        atomicAdd(out, ssum * (1.0f / (float)Bc));
    }
}

extern "C" void kernel_launch(void* const* d_in, const int* in_sizes, int n_in,
                              void* d_out, int out_size, void* d_ws, size_t ws_size,
                              hipStream_t stream) {
    const float* bridges = (const float*)d_in[0];
    const int*   b_inx   = (const int*)d_in[1];
    const int*   neg_i   = (const int*)d_in[2];
    const int*   neg_j   = (const int*)d_in[3];
    float*       out     = (float*)d_out;

    char* ws = (char*)d_ws;
    int*    cnt     = (int*)(ws + OFF_CNT);
    float4* rec     = (float4*)(ws + OFF_REC);
    float2* ppar    = (float2*)(ws + OFF_PPAR);
    float*  pos_dis = (float*)(ws + OFF_PD);
    float*  neg_dis = (float*)(ws + OFF_ND);

    hipMemsetAsync(cnt, 0, NR * sizeof(int), stream);
    k_build<<<NP / 256, 256, 0, stream>>>(b_inx, neg_i, neg_j, cnt, rec, ppar, neg_dis, out);
    k_main <<<NR / 4, 256, 0, stream>>>(bridges, cnt, rec, ppar, pos_dis, neg_dis);
    k_hinge<<<128, 256, 0, stream>>>(bridges, b_inx, neg_i, neg_j, pos_dis, neg_dis, out);
}